// Round 12
// baseline (258.715 us; speedup 1.0000x reference)
//
#include <hip/hip_runtime.h>

// GNN: 2x GCNConv(relu) + mean-pool + MLP head.
// Sizes fixed: N=50000, E=800000, F_IN=256, H=64, NG=64, NC=4.
//
// R9: hs/hb bf16, f32 accumulate. R10: deep gather pipeline.
// R11: dual-edge packed gather (2 edges/instr). R12: quad-edge packed gather
// — lane loads uint2 (4 bf16), 16 lanes/row, 4 edges per VMEM instruction
// (512B); quarters combined via shfl_xor(16)+shfl_xor(32).

#define TPB 256
#define CHUNK_A 4096
#define BCAP 4608          // per-bucket staging capacity (mean 4096, +8 sigma)

typedef unsigned short bfu;

__device__ __forceinline__ float bf2f(bfu u) {
    union { unsigned u32; float f; } c; c.u32 = ((unsigned)u) << 16; return c.f;
}
__device__ __forceinline__ bfu f2bf(float f) {
    union { float f; unsigned u; } c; c.f = f;
    unsigned r = 0x7FFFu + ((c.u >> 16) & 1u);     // round-to-nearest-even
    return (bfu)((c.u + r) >> 16);
}
__device__ __forceinline__ float blo(unsigned w) {
    union { unsigned u32; float f; } c; c.u32 = w << 16; return c.f;
}
__device__ __forceinline__ float bhi(unsigned w) {
    union { unsigned u32; float f; } c; c.u32 = w & 0xFFFF0000u; return c.f;
}

// ---------------- pass A: chunked bucket staging ----------------
// packed edge: (src<<8) | (dst & 255); requires n <= 65536, nbuck <= 256.

__global__ __launch_bounds__(TPB) void k_passA(const int* __restrict__ srcv,
                                               const int* __restrict__ dstv, int E,
                                               int* __restrict__ gcur,
                                               int* __restrict__ staged, int nbuck) {
    __shared__ int pk[CHUNK_A];
    __shared__ int hist[256];
    __shared__ int ebase[256];
    __shared__ int gbase[256];
    __shared__ int lcur[256];
    int t = threadIdx.x;
    int e0 = blockIdx.x * CHUNK_A;
    int e1 = e0 + CHUNK_A; if (e1 > E) e1 = E;

    hist[t] = 0; lcur[t] = 0;
    __syncthreads();
    for (int i = e0 + t; i < e1; i += TPB) atomicAdd(&hist[dstv[i] >> 8], 1);
    __syncthreads();
    int v = hist[t];
    ebase[t] = v;
    __syncthreads();
    for (int off = 1; off < 256; off <<= 1) {
        int u = (t >= off) ? ebase[t - off] : 0;
        __syncthreads();
        ebase[t] += u;
        __syncthreads();
    }
    ebase[t] -= v;
    if (t < nbuck && v > 0) gbase[t] = t * BCAP + atomicAdd(&gcur[t], v);
    __syncthreads();
    for (int i = e0 + t; i < e1; i += TPB) {
        int d = dstv[i];
        int s = srcv[i];
        int b = d >> 8;
        int r = atomicAdd(&lcur[b], 1);
        pk[ebase[b] + r] = (s << 8) | (d & 255);
    }
    __syncthreads();
    int wave = t >> 6, lane = t & 63;
    for (int b = wave; b < nbuck; b += 4) {
        int c = hist[b];
        int lb = ebase[b];
        int gb = gbase[b];
        for (int j = lane; j < c; j += 64) staged[gb + j] = pk[lb + j];
    }
}

// ---------------- pass B: per-bucket node sort + csr_off + dinv ----------------

__global__ __launch_bounds__(TPB) void k_passB(const int* __restrict__ staged,
                                               const int* __restrict__ gcur,
                                               int* __restrict__ csr_off,
                                               int* __restrict__ csr_src,
                                               float* __restrict__ dinv,
                                               int n, int nbuck) {
    __shared__ int pk[BCAP];
    __shared__ int soff[256];
    __shared__ int hist[256];
    __shared__ int nbase[256];
    __shared__ int cur[256];
    int b = blockIdx.x;
    int n0 = b << 8;
    int n1 = n0 + 256; if (n1 > n) n1 = n;
    int cnt = gcur[b];
    int t = threadIdx.x;

    int cv = (t < nbuck) ? gcur[t] : 0;
    soff[t] = cv;
    hist[t] = 0; cur[t] = 0;
    __syncthreads();
    for (int off = 1; off < 256; off <<= 1) {
        int u = (t >= off) ? soff[t - off] : 0;
        __syncthreads();
        soff[t] += u;
        __syncthreads();
    }
    int base = soff[b] - cnt;   // exclusive prefix at bucket b

    for (int i = t; i < cnt; i += TPB) pk[i] = staged[b * BCAP + i];
    __syncthreads();
    for (int i = t; i < cnt; i += TPB) atomicAdd(&hist[pk[i] & 255], 1);
    __syncthreads();
    int v = hist[t];
    nbase[t] = v;
    __syncthreads();
    for (int off = 1; off < 256; off <<= 1) {
        int u = (t >= off) ? nbase[t - off] : 0;
        __syncthreads();
        nbase[t] += u;
        __syncthreads();
    }
    nbase[t] -= v;
    if (n0 + t < n1) {
        csr_off[n0 + t] = base + nbase[t];
        dinv[n0 + t] = rsqrtf((float)(v + 1));   // +1 self loop
    }
    if (b == nbuck - 1 && t == 0) csr_off[n] = base + cnt;
    __syncthreads();
    for (int i = t; i < cnt; i += TPB) {
        int p = pk[i];
        int dloc = p & 255;
        int r = atomicAdd(&cur[dloc], 1);
        csr_src[base + nbase[dloc] + r] = p >> 8;
    }
}

// ---------------- GEMM: C[r][j] = dinv[r] * sum_k A[r][k] * W[k][j] ----------------

template <int K, bool BF16A>
__global__ __launch_bounds__(TPB) void k_gemm(const void* __restrict__ Av,
                                              const float* __restrict__ W,
                                              const float* __restrict__ dinv,
                                              bfu* __restrict__ C, int n) {
    __shared__ __align__(16) float Wc[64 * 64];
    __shared__ __align__(16) float xr[64 * 68];
    const int t = threadIdx.x;
    const int wave = t >> 6, lane = t & 63;
    const int li = lane >> 4, lj = lane & 15;
    const int rl0 = wave * 16 + li * 4;
    const int rbase = blockIdx.x * 64;

    float acc[4][4] = {{0.f,0.f,0.f,0.f},{0.f,0.f,0.f,0.f},{0.f,0.f,0.f,0.f},{0.f,0.f,0.f,0.f}};

    for (int kc = 0; kc < K; kc += 64) {
        {
            const float4* wsv = (const float4*)(W + (size_t)kc * 64);
            float4* wd = (float4*)Wc;
#pragma unroll
            for (int q = 0; q < 4; q++) wd[t + q * 256] = wsv[t + q * 256];
        }
        {
            int rl = t >> 2;
            int kq = (t & 3) * 16;
            int r = rbase + rl;
            if (!BF16A) {
                const float* A = (const float*)Av;
#pragma unroll
                for (int m = 0; m < 16; m += 4) {
                    float4 xv;
                    if (r < n) xv = *(const float4*)&A[(size_t)r * K + kc + kq + m];
                    else       xv = make_float4(0.f, 0.f, 0.f, 0.f);
                    *(float4*)&xr[rl * 68 + kq + m] = xv;
                }
            } else {
                const bfu* A = (const bfu*)Av;
                uint4 p0 = make_uint4(0,0,0,0), p1 = make_uint4(0,0,0,0);
                if (r < n) {
                    const uint4* ap = (const uint4*)(A + (size_t)r * K + kc + kq);
                    p0 = ap[0]; p1 = ap[1];
                }
                *(float4*)&xr[rl * 68 + kq + 0]  = make_float4(blo(p0.x), bhi(p0.x), blo(p0.y), bhi(p0.y));
                *(float4*)&xr[rl * 68 + kq + 4]  = make_float4(blo(p0.z), bhi(p0.z), blo(p0.w), bhi(p0.w));
                *(float4*)&xr[rl * 68 + kq + 8]  = make_float4(blo(p1.x), bhi(p1.x), blo(p1.y), bhi(p1.y));
                *(float4*)&xr[rl * 68 + kq + 12] = make_float4(blo(p1.z), bhi(p1.z), blo(p1.w), bhi(p1.w));
            }
        }
        __syncthreads();
#pragma unroll 8
        for (int kk = 0; kk < 64; kk++) {
            float4 wv = *(const float4*)&Wc[kk * 64 + lj * 4];
            float x0 = xr[(rl0 + 0) * 68 + kk];
            float x1 = xr[(rl0 + 1) * 68 + kk];
            float x2 = xr[(rl0 + 2) * 68 + kk];
            float x3 = xr[(rl0 + 3) * 68 + kk];
            acc[0][0] += x0 * wv.x; acc[0][1] += x0 * wv.y; acc[0][2] += x0 * wv.z; acc[0][3] += x0 * wv.w;
            acc[1][0] += x1 * wv.x; acc[1][1] += x1 * wv.y; acc[1][2] += x1 * wv.z; acc[1][3] += x1 * wv.w;
            acc[2][0] += x2 * wv.x; acc[2][1] += x2 * wv.y; acc[2][2] += x2 * wv.z; acc[2][3] += x2 * wv.w;
            acc[3][0] += x3 * wv.x; acc[3][1] += x3 * wv.y; acc[3][2] += x3 * wv.z; acc[3][3] += x3 * wv.w;
        }
        __syncthreads();
    }

#pragma unroll
    for (int ri = 0; ri < 4; ri++) {
        int r = rbase + rl0 + ri;
        if (r < n) {
            float d = dinv[r];
            ushort4 o;
            o.x = f2bf(acc[ri][0] * d);
            o.y = f2bf(acc[ri][1] * d);
            o.z = f2bf(acc[ri][2] * d);
            o.w = f2bf(acc[ri][3] * d);
            *(ushort4*)&C[(size_t)r * 64 + lj * 4] = o;
        }
    }
}

// ---------------- Aggregation: quad-edge packed gather ----------------
// Wave = 4 quarters of 16 lanes; lane handles 4 features (uint2 = 4 bf16).
// One gather instruction covers 4 edges (512B). Quarters combined by shfl_xor.

__global__ __launch_bounds__(TPB) void k_agg(const bfu* __restrict__ hs,
                                             const int* __restrict__ csr_off,
                                             const int* __restrict__ csr_src,
                                             const float* __restrict__ dinv,
                                             const float* __restrict__ bias,
                                             bfu* __restrict__ out, int n) {
    int node = blockIdx.x * 4 + (threadIdx.x >> 6);
    int lane = threadIdx.x & 63;
    int q = lane >> 4;             // quarter 0..3
    int fl = (lane & 15) * 4;      // feature base (4 features)
    if (node >= n) return;
    int p0 = csr_off[node];
    int p1 = csr_off[node + 1];

    float a0 = 0.f, a1 = 0.f, a2 = 0.f, a3 = 0.f;
    {   // self loop: quarter 0 only
        uint2 g = *(const uint2*)(hs + (size_t)node * 64 + fl);
        if (q == 0) { a0 = blo(g.x); a1 = bhi(g.x); a2 = blo(g.y); a3 = bhi(g.y); }
    }
    int p = p0;
    // 8 gathers in flight = 32 edges
    for (; p + 32 <= p1; p += 32) {
        int s[8]; uint2 g[8];
#pragma unroll
        for (int i = 0; i < 8; i++) s[i] = csr_src[p + 4 * i + q];
#pragma unroll
        for (int i = 0; i < 8; i++) g[i] = *(const uint2*)(hs + (size_t)s[i] * 64 + fl);
#pragma unroll
        for (int i = 0; i < 8; i++) {
            a0 += blo(g[i].x); a1 += bhi(g[i].x); a2 += blo(g[i].y); a3 += bhi(g[i].y);
        }
    }
    if (p + 16 <= p1) {
        int s[4]; uint2 g[4];
#pragma unroll
        for (int i = 0; i < 4; i++) s[i] = csr_src[p + 4 * i + q];
#pragma unroll
        for (int i = 0; i < 4; i++) g[i] = *(const uint2*)(hs + (size_t)s[i] * 64 + fl);
#pragma unroll
        for (int i = 0; i < 4; i++) {
            a0 += blo(g[i].x); a1 += bhi(g[i].x); a2 += blo(g[i].y); a3 += bhi(g[i].y);
        }
        p += 16;
    }
    if (p + 8 <= p1) {
        int s[2]; uint2 g[2];
#pragma unroll
        for (int i = 0; i < 2; i++) s[i] = csr_src[p + 4 * i + q];
#pragma unroll
        for (int i = 0; i < 2; i++) g[i] = *(const uint2*)(hs + (size_t)s[i] * 64 + fl);
#pragma unroll
        for (int i = 0; i < 2; i++) {
            a0 += blo(g[i].x); a1 += bhi(g[i].x); a2 += blo(g[i].y); a3 += bhi(g[i].y);
        }
        p += 8;
    }
    if (p + 4 <= p1) {
        int s = csr_src[p + q];
        uint2 g = *(const uint2*)(hs + (size_t)s * 64 + fl);
        a0 += blo(g.x); a1 += bhi(g.x); a2 += blo(g.y); a3 += bhi(g.y);
        p += 4;
    }
    // tail 0..3 edges: quarter 0 only
    if (q == 0) {
        for (int i = p; i < p1; i++) {
            int s = csr_src[i];
            uint2 g = *(const uint2*)(hs + (size_t)s * 64 + fl);
            a0 += blo(g.x); a1 += bhi(g.x); a2 += blo(g.y); a3 += bhi(g.y);
        }
    }
    // combine quarters (same fl in lanes differing by bits 4,5)
    a0 += __shfl_xor(a0, 16); a0 += __shfl_xor(a0, 32);
    a1 += __shfl_xor(a1, 16); a1 += __shfl_xor(a1, 32);
    a2 += __shfl_xor(a2, 16); a2 += __shfl_xor(a2, 32);
    a3 += __shfl_xor(a3, 16); a3 += __shfl_xor(a3, 32);

    float d = dinv[node];
    float4 bv = *(const float4*)(bias + fl);
    if (q == 0) {
        ushort4 o;
        o.x = f2bf(fmaxf(d * a0 + bv.x, 0.f));
        o.y = f2bf(fmaxf(d * a1 + bv.y, 0.f));
        o.z = f2bf(fmaxf(d * a2 + bv.z, 0.f));
        o.w = f2bf(fmaxf(d * a3 + bv.w, 0.f));
        *(ushort4*)(out + (size_t)node * 64 + fl) = o;
    }
}

// ---------------- Pool: sorted batch; uniform-chunk fast path (bf16 reads) ----------------

__global__ __launch_bounds__(TPB) void k_pool(const bfu* __restrict__ h,
                                              const int* __restrict__ batch, int n,
                                              float* __restrict__ gsum,
                                              int* __restrict__ gcnt) {
    const int CH = 16;
    int wid = blockIdx.x * 4 + (threadIdx.x >> 6);
    int lane = threadIdx.x & 63;
    int i0 = wid * CH;
    if (i0 >= n) return;
    int i1 = i0 + CH; if (i1 > n) i1 = n;
    int g0 = batch[i0];
    int g1 = batch[i1 - 1];
    if (g0 == g1) {
        float acc = 0.f;
#pragma unroll
        for (int i = 0; i < CH; i++) {
            int idx = i0 + i;
            if (idx < i1) acc += bf2f(h[(size_t)idx * 64 + lane]);
        }
        atomicAdd(&gsum[g0 * 64 + lane], acc);
        if (lane == 0) atomicAdd(&gcnt[g0], i1 - i0);
    } else {
        int cur = g0;
        float acc = 0.f;
        int cnt = 0;
        for (int i = i0; i < i1; i++) {
            int g = batch[i];
            if (g != cur) {
                atomicAdd(&gsum[cur * 64 + lane], acc);
                if (lane == 0) atomicAdd(&gcnt[cur], cnt);
                acc = 0.f; cnt = 0; cur = g;
            }
            acc += bf2f(h[(size_t)i * 64 + lane]);
            cnt++;
        }
        atomicAdd(&gsum[cur * 64 + lane], acc);
        if (lane == 0) atomicAdd(&gcnt[cur], cnt);
    }
}

// ---------------- Head, stage 1 ----------------

__global__ __launch_bounds__(TPB) void k_head1(const float* __restrict__ gsum,
                                               const int* __restrict__ gcnt,
                                               const float* __restrict__ fc1w,
                                               const float* __restrict__ fc1b,
                                               float* __restrict__ z) {
    int t = threadIdx.x;
    int g = blockIdx.x * 2 + (t >> 7);
    int o = t & 127;
    int c = gcnt[g]; if (c < 1) c = 1;
    float inv = 1.0f / (float)c;
    float a = fc1b[o];
#pragma unroll 16
    for (int j = 0; j < 64; j++) {
        float pj = gsum[g * 64 + j] * inv;
        a += pj * fc1w[j * 128 + o];
    }
    z[g * 128 + o] = fmaxf(a, 0.f);
}

// ---------------- Head, stage 2 ----------------

__global__ __launch_bounds__(TPB) void k_head2(const float* __restrict__ z,
                                               const float* __restrict__ fc2w,
                                               const float* __restrict__ fc2b,
                                               float* __restrict__ out) {
    int t = threadIdx.x;
    int g = t >> 2, c = t & 3;
    float a = fc2b[c];
#pragma unroll 16
    for (int o = 0; o < 128; o++) a += z[g * 128 + o] * fc2w[o * 4 + c];
    out[t] = a;
}

// ---------------- launch ----------------

extern "C" void kernel_launch(void* const* d_in, const int* in_sizes, int n_in,
                              void* d_out, int out_size, void* d_ws, size_t ws_size,
                              hipStream_t stream) {
    const float* x    = (const float*)d_in[0];
    const int*   ei   = (const int*)d_in[1];
    const int*   batch= (const int*)d_in[2];
    const float* W1   = (const float*)d_in[3];
    const float* b1   = (const float*)d_in[4];
    const float* W2   = (const float*)d_in[5];
    const float* b2   = (const float*)d_in[6];
    const float* fc1w = (const float*)d_in[7];
    const float* fc1b = (const float*)d_in[8];
    const float* fc2w = (const float*)d_in[9];
    const float* fc2b = (const float*)d_in[10];

    const int n = in_sizes[2];        // 50000
    const int E = in_sizes[1] / 2;    // 800000
    const int* srcv = ei;
    const int* dstv = ei + E;
    const int nbuck = (n + 255) >> 8; // 196 (must be <= 256)

    // workspace carve; zeroed region contiguous at front
    char* w = (char*)d_ws;
    int*   gcur   = (int*)w;            w += 256 * 4;
    int*   gcnt   = (int*)w;            w += 64 * 4;
    float* gsum   = (float*)w;          w += 64 * 64 * 4;
    size_t zbytes = (size_t)w - (size_t)d_ws;
    int*   csr_off= (int*)w;            w += (size_t)(n + 1) * 4;
    float* dinv   = (float*)w;          w += (size_t)n * 4;
    int*   csr_src= (int*)w;            w += (size_t)E * 4;
    int*   staged = (int*)w;            w += (size_t)nbuck * BCAP * 4;
    float* zbuf   = (float*)w;          w += 64 * 128 * 4;
    w = (char*)(((size_t)w + 255) & ~(size_t)255);
    bfu* hs = (bfu*)w;                  w += (size_t)n * 64 * 2;
    w = (char*)(((size_t)w + 255) & ~(size_t)255);
    bfu* hb = (bfu*)w;                  w += (size_t)n * 64 * 2;

    hipMemsetAsync(d_ws, 0, zbytes, stream);

    int gA = (E + CHUNK_A - 1) / CHUNK_A;   // 196
    k_passA<<<gA, TPB, 0, stream>>>(srcv, dstv, E, gcur, staged, nbuck);
    k_passB<<<nbuck, TPB, 0, stream>>>(staged, gcur, csr_off, csr_src, dinv, n, nbuck);

    int gRows = (n + 63) / 64;
    int gNode = (n + 3) / 4;
    k_gemm<256, false><<<gRows, TPB, 0, stream>>>(x, W1, dinv, hs, n);
    k_agg<<<gNode, TPB, 0, stream>>>(hs, csr_off, csr_src, dinv, b1, hb, n);
    k_gemm<64, true><<<gRows, TPB, 0, stream>>>(hb, W2, dinv, hs, n);
    k_agg<<<gNode, TPB, 0, stream>>>(hs, csr_off, csr_src, dinv, b2, hb, n);

    int nwaves16 = (n + 15) / 16;
    k_pool<<<(nwaves16 + 3) / 4, TPB, 0, stream>>>(hb, batch, n, gsum, gcnt);
    k_head1<<<32, TPB, 0, stream>>>(gsum, gcnt, fc1w, fc1b, zbuf);
    k_head2<<<1, TPB, 0, stream>>>(zbuf, fc2w, fc2b, (float*)d_out);
}

// Round 13
// 250.363 us; speedup vs baseline: 1.0334x; 1.0334x over previous
//
#include <hip/hip_runtime.h>

// GNN: 2x GCNConv(relu) + mean-pool + MLP head.
// Sizes fixed: N=50000, E=800000, F_IN=256, H=64, NG=64, NC=4.
//
// R9: hs/hb bf16, f32 accumulate. R10: deep gather pipeline.
// R11: dual-edge packed gather (2 edges per VMEM instr) — the measured
// sweet spot. R12's quad-pack regressed (fewer loads in flight at mean
// degree 17) and was reverted.

#define TPB 256
#define CHUNK_A 4096
#define BCAP 4608          // per-bucket staging capacity (mean 4096, +8 sigma)

typedef unsigned short bfu;

__device__ __forceinline__ float bf2f(bfu u) {
    union { unsigned u32; float f; } c; c.u32 = ((unsigned)u) << 16; return c.f;
}
__device__ __forceinline__ bfu f2bf(float f) {
    union { float f; unsigned u; } c; c.f = f;
    unsigned r = 0x7FFFu + ((c.u >> 16) & 1u);     // round-to-nearest-even
    return (bfu)((c.u + r) >> 16);
}
__device__ __forceinline__ float blo(unsigned w) {
    union { unsigned u32; float f; } c; c.u32 = w << 16; return c.f;
}
__device__ __forceinline__ float bhi(unsigned w) {
    union { unsigned u32; float f; } c; c.u32 = w & 0xFFFF0000u; return c.f;
}

// ---------------- pass A: chunked bucket staging ----------------
// packed edge: (src<<8) | (dst & 255); requires n <= 65536, nbuck <= 256.

__global__ __launch_bounds__(TPB) void k_passA(const int* __restrict__ srcv,
                                               const int* __restrict__ dstv, int E,
                                               int* __restrict__ gcur,
                                               int* __restrict__ staged, int nbuck) {
    __shared__ int pk[CHUNK_A];
    __shared__ int hist[256];
    __shared__ int ebase[256];
    __shared__ int gbase[256];
    __shared__ int lcur[256];
    int t = threadIdx.x;
    int e0 = blockIdx.x * CHUNK_A;
    int e1 = e0 + CHUNK_A; if (e1 > E) e1 = E;

    hist[t] = 0; lcur[t] = 0;
    __syncthreads();
    for (int i = e0 + t; i < e1; i += TPB) atomicAdd(&hist[dstv[i] >> 8], 1);
    __syncthreads();
    int v = hist[t];
    ebase[t] = v;
    __syncthreads();
    for (int off = 1; off < 256; off <<= 1) {
        int u = (t >= off) ? ebase[t - off] : 0;
        __syncthreads();
        ebase[t] += u;
        __syncthreads();
    }
    ebase[t] -= v;
    if (t < nbuck && v > 0) gbase[t] = t * BCAP + atomicAdd(&gcur[t], v);
    __syncthreads();
    for (int i = e0 + t; i < e1; i += TPB) {
        int d = dstv[i];
        int s = srcv[i];
        int b = d >> 8;
        int r = atomicAdd(&lcur[b], 1);
        pk[ebase[b] + r] = (s << 8) | (d & 255);
    }
    __syncthreads();
    int wave = t >> 6, lane = t & 63;
    for (int b = wave; b < nbuck; b += 4) {
        int c = hist[b];
        int lb = ebase[b];
        int gb = gbase[b];
        for (int j = lane; j < c; j += 64) staged[gb + j] = pk[lb + j];
    }
}

// ---------------- pass B: per-bucket node sort + csr_off + dinv ----------------

__global__ __launch_bounds__(TPB) void k_passB(const int* __restrict__ staged,
                                               const int* __restrict__ gcur,
                                               int* __restrict__ csr_off,
                                               int* __restrict__ csr_src,
                                               float* __restrict__ dinv,
                                               int n, int nbuck) {
    __shared__ int pk[BCAP];
    __shared__ int soff[256];
    __shared__ int hist[256];
    __shared__ int nbase[256];
    __shared__ int cur[256];
    int b = blockIdx.x;
    int n0 = b << 8;
    int n1 = n0 + 256; if (n1 > n) n1 = n;
    int cnt = gcur[b];
    int t = threadIdx.x;

    int cv = (t < nbuck) ? gcur[t] : 0;
    soff[t] = cv;
    hist[t] = 0; cur[t] = 0;
    __syncthreads();
    for (int off = 1; off < 256; off <<= 1) {
        int u = (t >= off) ? soff[t - off] : 0;
        __syncthreads();
        soff[t] += u;
        __syncthreads();
    }
    int base = soff[b] - cnt;   // exclusive prefix at bucket b

    for (int i = t; i < cnt; i += TPB) pk[i] = staged[b * BCAP + i];
    __syncthreads();
    for (int i = t; i < cnt; i += TPB) atomicAdd(&hist[pk[i] & 255], 1);
    __syncthreads();
    int v = hist[t];
    nbase[t] = v;
    __syncthreads();
    for (int off = 1; off < 256; off <<= 1) {
        int u = (t >= off) ? nbase[t - off] : 0;
        __syncthreads();
        nbase[t] += u;
        __syncthreads();
    }
    nbase[t] -= v;
    if (n0 + t < n1) {
        csr_off[n0 + t] = base + nbase[t];
        dinv[n0 + t] = rsqrtf((float)(v + 1));   // +1 self loop
    }
    if (b == nbuck - 1 && t == 0) csr_off[n] = base + cnt;
    __syncthreads();
    for (int i = t; i < cnt; i += TPB) {
        int p = pk[i];
        int dloc = p & 255;
        int r = atomicAdd(&cur[dloc], 1);
        csr_src[base + nbase[dloc] + r] = p >> 8;
    }
}

// ---------------- GEMM: C[r][j] = dinv[r] * sum_k A[r][k] * W[k][j] ----------------

template <int K, bool BF16A>
__global__ __launch_bounds__(TPB) void k_gemm(const void* __restrict__ Av,
                                              const float* __restrict__ W,
                                              const float* __restrict__ dinv,
                                              bfu* __restrict__ C, int n) {
    __shared__ __align__(16) float Wc[64 * 64];
    __shared__ __align__(16) float xr[64 * 68];
    const int t = threadIdx.x;
    const int wave = t >> 6, lane = t & 63;
    const int li = lane >> 4, lj = lane & 15;
    const int rl0 = wave * 16 + li * 4;
    const int rbase = blockIdx.x * 64;

    float acc[4][4] = {{0.f,0.f,0.f,0.f},{0.f,0.f,0.f,0.f},{0.f,0.f,0.f,0.f},{0.f,0.f,0.f,0.f}};

    for (int kc = 0; kc < K; kc += 64) {
        {
            const float4* wsv = (const float4*)(W + (size_t)kc * 64);
            float4* wd = (float4*)Wc;
#pragma unroll
            for (int q = 0; q < 4; q++) wd[t + q * 256] = wsv[t + q * 256];
        }
        {
            int rl = t >> 2;
            int kq = (t & 3) * 16;
            int r = rbase + rl;
            if (!BF16A) {
                const float* A = (const float*)Av;
#pragma unroll
                for (int m = 0; m < 16; m += 4) {
                    float4 xv;
                    if (r < n) xv = *(const float4*)&A[(size_t)r * K + kc + kq + m];
                    else       xv = make_float4(0.f, 0.f, 0.f, 0.f);
                    *(float4*)&xr[rl * 68 + kq + m] = xv;
                }
            } else {
                const bfu* A = (const bfu*)Av;
                uint4 p0 = make_uint4(0,0,0,0), p1 = make_uint4(0,0,0,0);
                if (r < n) {
                    const uint4* ap = (const uint4*)(A + (size_t)r * K + kc + kq);
                    p0 = ap[0]; p1 = ap[1];
                }
                *(float4*)&xr[rl * 68 + kq + 0]  = make_float4(blo(p0.x), bhi(p0.x), blo(p0.y), bhi(p0.y));
                *(float4*)&xr[rl * 68 + kq + 4]  = make_float4(blo(p0.z), bhi(p0.z), blo(p0.w), bhi(p0.w));
                *(float4*)&xr[rl * 68 + kq + 8]  = make_float4(blo(p1.x), bhi(p1.x), blo(p1.y), bhi(p1.y));
                *(float4*)&xr[rl * 68 + kq + 12] = make_float4(blo(p1.z), bhi(p1.z), blo(p1.w), bhi(p1.w));
            }
        }
        __syncthreads();
#pragma unroll 8
        for (int kk = 0; kk < 64; kk++) {
            float4 wv = *(const float4*)&Wc[kk * 64 + lj * 4];
            float x0 = xr[(rl0 + 0) * 68 + kk];
            float x1 = xr[(rl0 + 1) * 68 + kk];
            float x2 = xr[(rl0 + 2) * 68 + kk];
            float x3 = xr[(rl0 + 3) * 68 + kk];
            acc[0][0] += x0 * wv.x; acc[0][1] += x0 * wv.y; acc[0][2] += x0 * wv.z; acc[0][3] += x0 * wv.w;
            acc[1][0] += x1 * wv.x; acc[1][1] += x1 * wv.y; acc[1][2] += x1 * wv.z; acc[1][3] += x1 * wv.w;
            acc[2][0] += x2 * wv.x; acc[2][1] += x2 * wv.y; acc[2][2] += x2 * wv.z; acc[2][3] += x2 * wv.w;
            acc[3][0] += x3 * wv.x; acc[3][1] += x3 * wv.y; acc[3][2] += x3 * wv.z; acc[3][3] += x3 * wv.w;
        }
        __syncthreads();
    }

#pragma unroll
    for (int ri = 0; ri < 4; ri++) {
        int r = rbase + rl0 + ri;
        if (r < n) {
            float d = dinv[r];
            ushort4 o;
            o.x = f2bf(acc[ri][0] * d);
            o.y = f2bf(acc[ri][1] * d);
            o.z = f2bf(acc[ri][2] * d);
            o.w = f2bf(acc[ri][3] * d);
            *(ushort4*)&C[(size_t)r * 64 + lj * 4] = o;
        }
    }
}

// ---------------- Aggregation: dual-edge packed gather (R11) ----------------
// Wave = 2 halves of 32 lanes; lane handles 2 features (uint = 2 bf16).
// One gather instruction covers 2 edges (256B). Halves combined by shfl_xor.

__global__ __launch_bounds__(TPB) void k_agg(const bfu* __restrict__ hs,
                                             const int* __restrict__ csr_off,
                                             const int* __restrict__ csr_src,
                                             const float* __restrict__ dinv,
                                             const float* __restrict__ bias,
                                             bfu* __restrict__ out, int n) {
    int node = blockIdx.x * 4 + (threadIdx.x >> 6);
    int lane = threadIdx.x & 63;
    int half = lane >> 5;          // 0 or 1
    int fl = (lane & 31) * 2;      // feature pair base
    if (node >= n) return;
    int p0 = csr_off[node];
    int p1 = csr_off[node + 1];

    float ax = 0.f, ay = 0.f;
    {   // self loop: half 0 only
        unsigned g = *(const unsigned*)(hs + (size_t)node * 64 + fl);
        if (half == 0) { ax = blo(g); ay = bhi(g); }
    }
    int p = p0;
    // 8 edge-pairs = 16 edges in flight
    for (; p + 16 <= p1; p += 16) {
        int s[8]; unsigned g[8];
#pragma unroll
        for (int i = 0; i < 8; i++) s[i] = csr_src[p + 2 * i + half];
#pragma unroll
        for (int i = 0; i < 8; i++) g[i] = *(const unsigned*)(hs + (size_t)s[i] * 64 + fl);
#pragma unroll
        for (int i = 0; i < 8; i++) { ax += blo(g[i]); ay += bhi(g[i]); }
    }
    if (p + 8 <= p1) {
        int s[4]; unsigned g[4];
#pragma unroll
        for (int i = 0; i < 4; i++) s[i] = csr_src[p + 2 * i + half];
#pragma unroll
        for (int i = 0; i < 4; i++) g[i] = *(const unsigned*)(hs + (size_t)s[i] * 64 + fl);
#pragma unroll
        for (int i = 0; i < 4; i++) { ax += blo(g[i]); ay += bhi(g[i]); }
        p += 8;
    }
    if (p + 4 <= p1) {
        int s[2]; unsigned g[2];
#pragma unroll
        for (int i = 0; i < 2; i++) s[i] = csr_src[p + 2 * i + half];
#pragma unroll
        for (int i = 0; i < 2; i++) g[i] = *(const unsigned*)(hs + (size_t)s[i] * 64 + fl);
#pragma unroll
        for (int i = 0; i < 2; i++) { ax += blo(g[i]); ay += bhi(g[i]); }
        p += 4;
    }
    if (p + 2 <= p1) {
        int s = csr_src[p + half];
        unsigned g = *(const unsigned*)(hs + (size_t)s * 64 + fl);
        ax += blo(g); ay += bhi(g);
        p += 2;
    }
    if (p < p1) {   // odd tail: half 0 only
        int s = csr_src[p];
        unsigned g = *(const unsigned*)(hs + (size_t)s * 64 + fl);
        if (half == 0) { ax += blo(g); ay += bhi(g); }
    }
    // combine halves (same fl in lane and lane^32)
    ax += __shfl_xor(ax, 32);
    ay += __shfl_xor(ay, 32);

    float d = dinv[node];
    float vx = fmaxf(d * ax + bias[fl + 0], 0.f);
    float vy = fmaxf(d * ay + bias[fl + 1], 0.f);
    if (half == 0) {
        ushort2 o;
        o.x = f2bf(vx);
        o.y = f2bf(vy);
        *(ushort2*)(out + (size_t)node * 64 + fl) = o;
    }
}

// ---------------- Pool: sorted batch; uniform-chunk fast path (bf16 reads) ----------------

__global__ __launch_bounds__(TPB) void k_pool(const bfu* __restrict__ h,
                                              const int* __restrict__ batch, int n,
                                              float* __restrict__ gsum,
                                              int* __restrict__ gcnt) {
    const int CH = 16;
    int wid = blockIdx.x * 4 + (threadIdx.x >> 6);
    int lane = threadIdx.x & 63;
    int i0 = wid * CH;
    if (i0 >= n) return;
    int i1 = i0 + CH; if (i1 > n) i1 = n;
    int g0 = batch[i0];
    int g1 = batch[i1 - 1];
    if (g0 == g1) {
        float acc = 0.f;
#pragma unroll
        for (int i = 0; i < CH; i++) {
            int idx = i0 + i;
            if (idx < i1) acc += bf2f(h[(size_t)idx * 64 + lane]);
        }
        atomicAdd(&gsum[g0 * 64 + lane], acc);
        if (lane == 0) atomicAdd(&gcnt[g0], i1 - i0);
    } else {
        int cur = g0;
        float acc = 0.f;
        int cnt = 0;
        for (int i = i0; i < i1; i++) {
            int g = batch[i];
            if (g != cur) {
                atomicAdd(&gsum[cur * 64 + lane], acc);
                if (lane == 0) atomicAdd(&gcnt[cur], cnt);
                acc = 0.f; cnt = 0; cur = g;
            }
            acc += bf2f(h[(size_t)i * 64 + lane]);
            cnt++;
        }
        atomicAdd(&gsum[cur * 64 + lane], acc);
        if (lane == 0) atomicAdd(&gcnt[cur], cnt);
    }
}

// ---------------- Head, stage 1 ----------------

__global__ __launch_bounds__(TPB) void k_head1(const float* __restrict__ gsum,
                                               const int* __restrict__ gcnt,
                                               const float* __restrict__ fc1w,
                                               const float* __restrict__ fc1b,
                                               float* __restrict__ z) {
    int t = threadIdx.x;
    int g = blockIdx.x * 2 + (t >> 7);
    int o = t & 127;
    int c = gcnt[g]; if (c < 1) c = 1;
    float inv = 1.0f / (float)c;
    float a = fc1b[o];
#pragma unroll 16
    for (int j = 0; j < 64; j++) {
        float pj = gsum[g * 64 + j] * inv;
        a += pj * fc1w[j * 128 + o];
    }
    z[g * 128 + o] = fmaxf(a, 0.f);
}

// ---------------- Head, stage 2 ----------------

__global__ __launch_bounds__(TPB) void k_head2(const float* __restrict__ z,
                                               const float* __restrict__ fc2w,
                                               const float* __restrict__ fc2b,
                                               float* __restrict__ out) {
    int t = threadIdx.x;
    int g = t >> 2, c = t & 3;
    float a = fc2b[c];
#pragma unroll 16
    for (int o = 0; o < 128; o++) a += z[g * 128 + o] * fc2w[o * 4 + c];
    out[t] = a;
}

// ---------------- launch ----------------

extern "C" void kernel_launch(void* const* d_in, const int* in_sizes, int n_in,
                              void* d_out, int out_size, void* d_ws, size_t ws_size,
                              hipStream_t stream) {
    const float* x    = (const float*)d_in[0];
    const int*   ei   = (const int*)d_in[1];
    const int*   batch= (const int*)d_in[2];
    const float* W1   = (const float*)d_in[3];
    const float* b1   = (const float*)d_in[4];
    const float* W2   = (const float*)d_in[5];
    const float* b2   = (const float*)d_in[6];
    const float* fc1w = (const float*)d_in[7];
    const float* fc1b = (const float*)d_in[8];
    const float* fc2w = (const float*)d_in[9];
    const float* fc2b = (const float*)d_in[10];

    const int n = in_sizes[2];        // 50000
    const int E = in_sizes[1] / 2;    // 800000
    const int* srcv = ei;
    const int* dstv = ei + E;
    const int nbuck = (n + 255) >> 8; // 196 (must be <= 256)

    // workspace carve; zeroed region contiguous at front
    char* w = (char*)d_ws;
    int*   gcur   = (int*)w;            w += 256 * 4;
    int*   gcnt   = (int*)w;            w += 64 * 4;
    float* gsum   = (float*)w;          w += 64 * 64 * 4;
    size_t zbytes = (size_t)w - (size_t)d_ws;
    int*   csr_off= (int*)w;            w += (size_t)(n + 1) * 4;
    float* dinv   = (float*)w;          w += (size_t)n * 4;
    int*   csr_src= (int*)w;            w += (size_t)E * 4;
    int*   staged = (int*)w;            w += (size_t)nbuck * BCAP * 4;
    float* zbuf   = (float*)w;          w += 64 * 128 * 4;
    w = (char*)(((size_t)w + 255) & ~(size_t)255);
    bfu* hs = (bfu*)w;                  w += (size_t)n * 64 * 2;
    w = (char*)(((size_t)w + 255) & ~(size_t)255);
    bfu* hb = (bfu*)w;                  w += (size_t)n * 64 * 2;

    hipMemsetAsync(d_ws, 0, zbytes, stream);

    int gA = (E + CHUNK_A - 1) / CHUNK_A;   // 196
    k_passA<<<gA, TPB, 0, stream>>>(srcv, dstv, E, gcur, staged, nbuck);
    k_passB<<<nbuck, TPB, 0, stream>>>(staged, gcur, csr_off, csr_src, dinv, n, nbuck);

    int gRows = (n + 63) / 64;
    int gNode = (n + 3) / 4;
    k_gemm<256, false><<<gRows, TPB, 0, stream>>>(x, W1, dinv, hs, n);
    k_agg<<<gNode, TPB, 0, stream>>>(hs, csr_off, csr_src, dinv, b1, hb, n);
    k_gemm<64, true><<<gRows, TPB, 0, stream>>>(hb, W2, dinv, hs, n);
    k_agg<<<gNode, TPB, 0, stream>>>(hs, csr_off, csr_src, dinv, b2, hb, n);

    int nwaves16 = (n + 15) / 16;
    k_pool<<<(nwaves16 + 3) / 4, TPB, 0, stream>>>(hb, batch, n, gsum, gcnt);
    k_head1<<<32, TPB, 0, stream>>>(gsum, gcnt, fc1w, fc1b, zbuf);
    k_head2<<<1, TPB, 0, stream>>>(zbuf, fc2w, fc2b, (float*)d_out);
}